// Round 10
// baseline (154.949 us; speedup 1.0000x reference)
//
#include <hip/hip_runtime.h>
#include <hip/hip_bf16.h>

typedef unsigned short u16;
typedef unsigned int   u32;
typedef __attribute__((ext_vector_type(2))) u32   u32x2;
typedef __attribute__((ext_vector_type(4))) float f32x4;
typedef __attribute__((ext_vector_type(4))) u32   u32x4;
typedef __attribute__((ext_vector_type(8))) short bf16x8;

#define HWPIX  9216
#define NPIX   73728
#define LN_EPS 1e-5f
#define MROW   64       // pixels per block
#define HSTR   264      // hn row stride (elems): 256 + 8 pad (incl. 2-ch wrap pad)
#define ASTR   40       // afg chunk row stride (elems): 32 + 8 pad

template<int N> struct IC { static constexpr int value = N; };

__device__ __forceinline__ u16 f2bf(float f){
  u32 u = __builtin_bit_cast(u32, f);
  u += 0x7fffu + ((u >> 16) & 1u);          // RTNE
  return (u16)(u >> 16);
}
__device__ __forceinline__ u32 pkbf(float lo, float hi){   // 1 inst packed cvt
  u32 d;
  asm("v_cvt_pk_bf16_f32 %0, %1, %2" : "=v"(d) : "v"(lo), "v"(hi));
  return d;
}
__device__ __forceinline__ float lo2f(u32 w){ return __builtin_bit_cast(float, w << 16); }
__device__ __forceinline__ float hi2f(u32 w){ return __builtin_bit_cast(float, w & 0xffff0000u); }
__device__ __forceinline__ float bfu2f(u16 h){ return __builtin_bit_cast(float, (u32)h << 16); }
__device__ __forceinline__ float fsigmoid(float v){ return __fdividef(1.f, 1.f + __expf(-v)); }
__device__ __forceinline__ float fsilu(float v){ return __fdividef(v, 1.f + __expf(-v)); }

__device__ __forceinline__ void gld16(const u16* g, u16* l){
  __builtin_amdgcn_global_load_lds((const __attribute__((address_space(1))) void*)g,
                                   (__attribute__((address_space(3))) void*)l,
                                   16, 0, 0);
}

// ---------------- kernel 1: weight convert (dot + gate) into staging layout --------
__global__ __launch_bounds__(256) void wconv(const float* __restrict__ pk,
                                             const float* __restrict__ gk,
                                             u16* __restrict__ wsdot,   // 16 chunks
                                             u16* __restrict__ wsgate)  // 16 chunks
{
  int gid = blockIdx.x * 256 + threadIdx.x;   // 32768 = 128 blocks
  int t = gid >> 10, S = gid & 1023;
  int q = (S >> 2) & 15, pp = S & 3, w8 = (S >> 6) & 7, rb = S >> 9;
  int n  = rb * 128 + w8 * 16 + q;
  int kq = pp ^ ((q >> 1) & 3);
  const float* W; int k0; u16* dst;
  if (t < 8)       { W = pk; k0 =       t      * 32 + kq * 8; dst = wsdot  + (size_t)t * 8192; }
  else if (t < 16) { W = pk; k0 = 512 + (t-8)  * 32 + kq * 8; dst = wsdot  + (size_t)t * 8192; }
  else             { W = gk; k0 =       (t-16) * 32 + kq * 8; dst = wsgate + (size_t)(t-16) * 8192; }
  u32 ow[4];
  #pragma unroll
  for (int e = 0; e < 4; ++e) {
    float f0 = W[(size_t)(k0 + 2*e)     * 256 + n];
    float f1 = W[(size_t)(k0 + 2*e + 1) * 256 + n];
    ow[e] = (u32)f2bf(f0) | ((u32)f2bf(f1) << 16);
  }
  *(u32x4*)(dst + (size_t)S * 8) = (u32x4){ow[0], ow[1], ow[2], ow[3]};
}

// ---------------- kernel 2: per-(b,h) partial sums of h_norm over w ----------------
__global__ __launch_bounds__(256) void ln_partial(const float* __restrict__ x,
                                                  const float* __restrict__ g,
                                                  const float* __restrict__ bt,
                                                  float* __restrict__ partial) // [768][256]
{
  const int bh = blockIdx.x;
  const int tid = threadIdx.x;
  const int wv = tid >> 6, lane = tid & 63;
  const float* xrow = x + (size_t)bh * 96 * 256;
  __shared__ float red[4][256];

  f32x4 gv = *(const f32x4*)(g  + lane * 4);
  f32x4 bv = *(const f32x4*)(bt + lane * 4);
  f32x4 acc = {0.f, 0.f, 0.f, 0.f};

  for (int w = wv; w < 96; w += 4) {
    f32x4 v = *(const f32x4*)(xrow + w * 256 + lane * 4);
    float s  = v[0] + v[1] + v[2] + v[3];
    float s2 = v[0]*v[0] + v[1]*v[1] + v[2]*v[2] + v[3]*v[3];
    #pragma unroll
    for (int m = 1; m < 64; m <<= 1) { s += __shfl_xor(s, m); s2 += __shfl_xor(s2, m); }
    float mu  = s * (1.f / 256.f);
    float var = s2 * (1.f / 256.f) - mu * mu;
    float rs  = rsqrtf(var + LN_EPS);
    #pragma unroll
    for (int j = 0; j < 4; ++j) acc[j] += (v[j] - mu) * rs * gv[j] + bv[j];
  }
  *(f32x4*)(&red[wv][lane * 4]) = acc;
  __syncthreads();
  float s = red[0][tid] + red[1][tid] + red[2][tid] + red[3][tid];
  partial[(size_t)bh * 256 + tid] = s;
}

// ---------------- kernel 3: reduce rows -> spatial mean [8][258] (wrap-padded) -----
__global__ __launch_bounds__(256) void ln_mean(const float* __restrict__ partial,
                                               float* __restrict__ mean)
{
  int b = blockIdx.x, c = threadIdx.x;
  float s = 0.f;
  for (int h = 0; h < 96; ++h) s += partial[((size_t)b * 96 + h) * 256 + c];
  float m = s * (1.f / 9216.f);
  mean[b * 258 + c] = m;
  if (c < 2) mean[b * 258 + 256 + c] = m;
}

// ---------------- kernel 4: fold wedge into per-batch weights ----------------------
__global__ __launch_bounds__(256) void wfold(const float* __restrict__ pk,
                                             const float* __restrict__ meang,
                                             u16* __restrict__ wsW)
{
  __shared__ float msh[256];
  int gid = blockIdx.x * 256 + threadIdx.x;   // 65536 = 256 blocks
  int chunk = gid >> 10;                      // 0..63 (uniform per block)
  int b = chunk >> 3, j = chunk & 7;
  msh[threadIdx.x] = meang[b * 258 + threadIdx.x];
  __syncthreads();
  int S = gid & 1023;
  int q = (S >> 2) & 15, pp = S & 3, w8 = (S >> 6) & 7, rb = S >> 9;
  int n  = rb * 128 + w8 * 16 + q;
  int kq = pp ^ ((q >> 1) & 3);
  u32 ow[4];
  #pragma unroll
  for (int e = 0; e < 4; ++e) {
    float r[2];
    #pragma unroll
    for (int hh = 0; hh < 2; ++hh) {
      int c = j * 32 + kq * 8 + 2 * e + hh;
      int cm1 = (c + 255) & 255, cm2 = (c + 254) & 255;
      int cp1 = (c + 1) & 255,   cp2 = (c + 2) & 255;
      r[hh] = msh[cm1] * pk[(size_t)(256 + cm1) * 256 + n]
            - msh[cp1] * pk[(size_t)(256 + c)   * 256 + n]
            + msh[cm2] * pk[(size_t)(768 + cm2) * 256 + n]
            - msh[cp2] * pk[(size_t)(768 + c)   * 256 + n];
    }
    ow[e] = (u32)f2bf(r[0]) | ((u32)f2bf(r[1]) << 16);
  }
  *(u32x4*)(wsW + (size_t)chunk * 8192 + (size_t)S * 8) = (u32x4){ow[0], ow[1], ow[2], ow[3]};
}

// ---------------- kernel 5: fused main ---------------------------------------------
// r9 skeleton; B staging switched to global_load_lds DMA (r3's proven asm pattern:
// explicit s_waitcnt + raw s_barrier) -> writeB's 16KB/step wave-issued LDS writes
// and its vmcnt-coupled stall leave the critical path. s_setprio(1) around MFMA (T5).
__global__ __launch_bounds__(512, 4) void fused(
    const float* __restrict__ x,
    const float* __restrict__ lng, const float* __restrict__ lnb,
    const u16* __restrict__ wsdot, const u16* __restrict__ wsW,
    const u16* __restrict__ wsgate,
    const float* __restrict__ pbias, const float* __restrict__ gbias,
    const float* __restrict__ gamma, const float* __restrict__ meang,
    float* __restrict__ out)
{
  __shared__ u16 hn[MROW * HSTR];       // 33792 B  h_norm bf16 (persists)
  __shared__ u16 afg[2][MROW * ASTR];   // 10240 B  A chunk dbuf (segs 0,1,4)
  __shared__ u16 Bl [2][8192];          // 32768 B  B chunk dbuf (DMA-staged)
  __shared__ float msh[258];            //  1032 B  spatial mean (wrap-padded)

  const int tid  = threadIdx.x;
  const long pix0 = (long)blockIdx.x * MROW;
  const int bat  = (int)(pix0 / HWPIX);      // 9216 % 64 == 0

  const int wave = tid >> 6, lane = tid & 63;
  const int wr = wave & 1, wc = wave >> 1;       // 2x4 wave grid
  const int fr = lane & 15, kq = lane >> 4;
  const int bswz = (kq ^ ((fr >> 1) & 3)) * 8;
  const int br = tid >> 3, bo = (tid & 7) * 4;   // feats build: row, 4-ch slice

  f32x4 acc[2][4];
  #pragma unroll
  for (int i = 0; i < 2; ++i)
    #pragma unroll
    for (int j = 0; j < 4; ++j) acc[i][j] = (f32x4){0.f, 0.f, 0.f, 0.f};
  u32 gfp[2][4][2];

  auto sgptr = [&](auto SG) -> const u16* {
    constexpr int sg = decltype(SG)::value;
    if constexpr      (sg == 0) return wsdot;
    else if constexpr (sg == 1) return wsdot + 8 * 8192;
    else if constexpr (sg == 2) return wsW + (size_t)bat * 65536;
    else if constexpr (sg == 3) return wsgate;
    else                        return wsgate + 8 * 8192;
  };
  // DMA-stage chunk u into Bl[buf]: 2 x global_load_lds dwordx4 per thread.
  // dst is wave-uniform base; HW adds lane*16B (guide §5 caveat).
  auto stageB = [&](auto UC, int buf) {
    constexpr int u = decltype(UC)::value;
    const u16* src = sgptr(IC<(u >> 3)>{}) + (size_t)(u & 7) * 8192 + tid * 8;
    u16* dst = &Bl[buf][wave * 512];
    gld16(src, dst);
    gld16(src + 4096, dst + 4096);
  };

  stageB(IC<0>{}, 0);                 // chunk 0 -> Bl[0], lands during preproc

  if (tid < 258) msh[tid] = meang[bat * 258 + tid];

  float pbv[4];
  #pragma unroll
  for (int nt = 0; nt < 4; ++nt) pbv[nt] = pbias[wc * 64 + nt * 16 + fr];

  // ---- preproc (2-pass): LN -> hn (8 lanes/pixel, 32 ch each) ----
  {
    const int p = tid >> 3, o = tid & 7;
    const float* xp = x + (pix0 + p) * 256 + o * 32;
    float s = 0.f, s2 = 0.f;
    #pragma unroll
    for (int i = 0; i < 8; ++i) {
      f32x4 v = *(const f32x4*)(xp + i * 4);
      s  += v[0] + v[1] + v[2] + v[3];
      s2 += v[0]*v[0] + v[1]*v[1] + v[2]*v[2] + v[3]*v[3];
    }
    s += __shfl_xor(s, 1); s2 += __shfl_xor(s2, 1);
    s += __shfl_xor(s, 2); s2 += __shfl_xor(s2, 2);
    s += __shfl_xor(s, 4); s2 += __shfl_xor(s2, 4);
    float mu  = s * (1.f / 256.f);
    float var = s2 * (1.f / 256.f) - mu * mu;
    float rs  = rsqrtf(var + LN_EPS);

    const float* gp = lng + o * 32;
    const float* bp = lnb + o * 32;
    u16* zd = hn + p * HSTR + o * 32;
    #pragma unroll
    for (int i = 0; i < 8; ++i) {
      f32x4 v  = *(const f32x4*)(xp + i * 4);     // L2-hot reload
      f32x4 gg = *(const f32x4*)(gp + i * 4);
      f32x4 bb = *(const f32x4*)(bp + i * 4);
      float h0 = (v[0] - mu) * rs * gg[0] + bb[0];
      float h1 = (v[1] - mu) * rs * gg[1] + bb[1];
      float h2 = (v[2] - mu) * rs * gg[2] + bb[2];
      float h3 = (v[3] - mu) * rs * gg[3] + bb[3];
      u32 d0 = pkbf(h0, h1);
      u32 d1 = pkbf(h2, h3);
      *(u32*)(zd + i * 4)     = d0;
      *(u32*)(zd + i * 4 + 2) = d1;
      if (i == 0 && o == 0) *(u32*)(hn + p * HSTR + 256) = d0;  // wrap pad
    }
  }

  // dot feats for shift s (compile-time), window w -> afg[buf]
  auto featsD = [&](auto SC, int w, int buf) {
    constexpr int s = decltype(SC)::value;
    const int cc = w * 32 + bo;
    const u16* zp = hn + br * HSTR + cc;
    u32x2 aa = *(const u32x2*)(zp);              // b64
    u32 a2   = *(const u32*)(zp + 4);            // b32
    float h0 = lo2f(aa[0]), h1 = hi2f(aa[0]), h2 = lo2f(aa[1]);
    float h3 = hi2f(aa[1]), h4 = lo2f(a2), h5 = hi2f(a2);
    float m0 = msh[cc + s], m1 = msh[cc + s + 1];
    float m2 = msh[cc + s + 2], m3 = msh[cc + s + 3];
    float t0, t1, t2, t3;
    if constexpr (s == 1) { t0 = h1; t1 = h2; t2 = h3; t3 = h4; }
    else                  { t0 = h2; t1 = h3; t2 = h4; t3 = h5; }
    float r0 = fsilu(h0 * (t0 - m0));
    float r1 = fsilu(h1 * (t1 - m1));
    float r2 = fsilu(h2 * (t2 - m2));
    float r3 = fsilu(h3 * (t3 - m3));
    *(u32*)(&afg[buf][br * ASTR + bo])     = pkbf(r0, r1);
    *(u32*)(&afg[buf][br * ASTR + bo + 2]) = pkbf(r2, r3);
  };

  // g_feat chunk cg (compile-time) from packed regs into afg
  auto gfcopy = [&](auto CGC, int buf) {
    constexpr int cg = decltype(CGC)::value;
    constexpr int par = cg & 1;
    if (wc == (cg >> 1)) {
      #pragma unroll
      for (int v = 0; v < 2; ++v) {
        #pragma unroll
        for (int ai = 0; ai < 2; ++ai)
          #pragma unroll
          for (int rp = 0; rp < 2; ++rp) {
            u32 pw = gfp[ai][par * 2 + v][rp];
            int row0 = wr * 32 + ai * 16 + kq * 4 + rp * 2;
            afg[buf][row0 * ASTR + v * 16 + fr]       = (u16)pw;
            afg[buf][(row0 + 1) * ASTR + v * 16 + fr] = (u16)(pw >> 16);
          }
      }
    }
  };

  auto domfma = [&](const u16* abase, int astr, int buf) {
    bf16x8 av0 = *(const bf16x8*)(abase);
    bf16x8 av1 = *(const bf16x8*)(abase + 16 * astr);
    const u16* bp = &Bl[buf][wc * 2048 + fr * 32 + bswz];
    __builtin_amdgcn_s_setprio(1);
    #pragma unroll
    for (int nt = 0; nt < 4; ++nt) {
      bf16x8 bv = *(const bf16x8*)(bp + nt * 512);
      acc[0][nt] = __builtin_amdgcn_mfma_f32_16x16x32_bf16(av0, bv, acc[0][nt], 0, 0, 0);
      acc[1][nt] = __builtin_amdgcn_mfma_f32_16x16x32_bf16(av1, bv, acc[1][nt], 0, 0, 0);
    }
    __builtin_amdgcn_s_setprio(0);
  };

  // barrier 1: hn/msh ds_writes drained; stage(0) DMA drained (vmcnt)
  asm volatile("s_waitcnt vmcnt(0) lgkmcnt(0)" ::: "memory");
  __builtin_amdgcn_s_barrier();
  featsD(IC<1>{}, 0, 0);              // afg[0] = dot s=1 window 0 (cross-thread hn)
  asm volatile("s_waitcnt lgkmcnt(0)" ::: "memory");
  __builtin_amdgcn_s_barrier();       // afg[0] visible

  auto stepfn = [&](auto SEGC, auto JC) {
    constexpr int SEG = decltype(SEGC)::value;
    constexpr int j   = decltype(JC)::value;
    constexpr int t   = SEG * 8 + j;
    constexpr int cb  = t & 1, nb = cb ^ 1;
    constexpr int u   = t + 1;                    // chunk to stage+build
    if constexpr (u < 40) stageB(IC<u>{}, nb);    // DMA issue: a full step to land
    if constexpr (SEG == 0 || SEG == 1 || SEG == 4)
      domfma(&afg[cb][(wr * 32 + fr) * ASTR + kq * 8], ASTR, cb);
    else
      domfma(&hn[(wr * 32 + fr) * HSTR + j * 32 + kq * 8], HSTR, cb);
    constexpr int useg = u >> 3;
    if constexpr (u < 40) {
      if constexpr      (useg == 0) featsD(IC<1>{}, u & 7, nb);
      else if constexpr (useg == 1) featsD(IC<2>{}, u & 7, nb);
      else if constexpr (useg == 4) gfcopy(IC<u - 32>{}, nb);
    }
    if constexpr (t == 23) {          // end of GEMM1: fold to packed bf16 g_feat
      #pragma unroll
      for (int nt = 0; nt < 4; ++nt)
        #pragma unroll
        for (int ai = 0; ai < 2; ++ai) {
          f32x4 a = acc[ai][nt];
          gfp[ai][nt][0] = pkbf(a[0] + pbv[nt], a[1] + pbv[nt]);
          gfp[ai][nt][1] = pkbf(a[2] + pbv[nt], a[3] + pbv[nt]);
          acc[ai][nt] = (f32x4){0.f, 0.f, 0.f, 0.f};
        }
    }
    // drain this step's DMA (into nb) + afg ds_writes, then barrier
    asm volatile("s_waitcnt vmcnt(0) lgkmcnt(0)" ::: "memory");
    __builtin_amdgcn_s_barrier();
  };
  auto runseg = [&](auto SEGC) {
    stepfn(SEGC, IC<0>{}); stepfn(SEGC, IC<1>{});
    stepfn(SEGC, IC<2>{}); stepfn(SEGC, IC<3>{});
    stepfn(SEGC, IC<4>{}); stepfn(SEGC, IC<5>{});
    stepfn(SEGC, IC<6>{}); stepfn(SEGC, IC<7>{});
  };
  runseg(IC<0>{}); runseg(IC<1>{}); runseg(IC<2>{});
  runseg(IC<3>{}); runseg(IC<4>{});

  // ---- final epilogue: alpha, silu, LayerScale, residual ----
  float gbv[4], gmv[4];
  #pragma unroll
  for (int nt = 0; nt < 4; ++nt) {
    int col = wc * 64 + nt * 16 + fr;
    gbv[nt] = gbias[col]; gmv[nt] = gamma[col];
  }
  #pragma unroll
  for (int ai = 0; ai < 2; ++ai)
    #pragma unroll
    for (int rr = 0; rr < 4; ++rr) {
      const int row = wr * 32 + ai * 16 + kq * 4 + rr;
      const long pix = pix0 + row;
      #pragma unroll
      for (int nt = 0; nt < 4; ++nt) {
        int col = wc * 64 + nt * 16 + fr;
        float xv = x[pix * 256 + col];
        float hh = bfu2f(hn[row * HSTR + col]);
        u32 pw = gfp[ai][nt][rr >> 1];
        float gfv = bfu2f((u16)((rr & 1) ? (pw >> 16) : pw));
        float al = fsigmoid(acc[ai][nt][rr] + gbv[nt]);
        out[pix * 256 + col] = xv + (fsilu(hh) + al * gfv) * gmv[nt];
      }
    }
}

extern "C" void kernel_launch(void* const* d_in, const int* in_sizes, int n_in,
                              void* d_out, int out_size, void* d_ws, size_t ws_size,
                              hipStream_t stream) {
  const float* x     = (const float*)d_in[0];
  const float* lng   = (const float*)d_in[1];
  const float* lnb   = (const float*)d_in[2];
  const float* pk    = (const float*)d_in[3];
  const float* pbias = (const float*)d_in[4];
  const float* gk    = (const float*)d_in[5];
  const float* gbias = (const float*)d_in[6];
  const float* gamma = (const float*)d_in[7];
  float* out = (float*)d_out;

  char* ws = (char*)d_ws;
  u16*   wsdot   = (u16*)ws;                       // 262144 B (16 chunks)
  u16*   wsgate  = (u16*)(ws + 262144);            // 262144 B (16 chunks)
  float* meang   = (float*)(ws + 524288);          // 8256 B
  u16*   wsW     = (u16*)(ws + 532544);            // 1048576 B (64 chunks, per-batch W')
  float* partial = (float*)(ws + 532544);          // 786432 B — dead before wfold writes W'

  wconv<<<128, 256, 0, stream>>>(pk, gk, wsdot, wsgate);
  ln_partial<<<768, 256, 0, stream>>>(x, lng, lnb, partial);
  ln_mean<<<8, 256, 0, stream>>>(partial, meang);
  wfold<<<256, 256, 0, stream>>>(pk, meang, wsW);
  fused<<<NPIX / MROW, 512, 0, stream>>>(x, lng, lnb, wsdot, wsW, wsgate,
                                         pbias, gbias, gamma, meang, out);
}